// Round 5
// baseline (294.035 us; speedup 1.0000x reference)
//
#include <hip/hip_runtime.h>

typedef unsigned short u16;
typedef __attribute__((ext_vector_type(8))) short s16x8;   // 8 x bf16 frag (verified form)
typedef __attribute__((ext_vector_type(4))) float floatx4;

// xt (per batch): [cg=16][row=66][col=66][c32=32] bf16, spatial-padded NCHW32c
// SWIZZLED: within each 64B (row,col) channel-group, c32 index ^= ((col>>1)&3)<<3
#define XT_ROWELEMS 2112                 // 66*32
#define XT_CGELEMS  139392               // 66*66*32
#define XT_PB       4460544ull           // 16*66*66*32*2 bytes per batch
// wmod (per batch): [t=9][cg=16][o512=512][c32=32] bf16  (o512 contiguous for M=256 tiles)
// SWIZZLED: within each 64B o-row, c32 index ^= ((o>>1)&3)<<3
#define WM_ELEMS    2359296ull           // 9*16*512*32 elems per batch
#define WM_PB       4718592ull           // bytes per batch

// async global->LDS DMA, 16B per lane; lds dest = wave-uniform base + lane*16
#define GLDS(gp, lp) __builtin_amdgcn_global_load_lds(                      \
    (const __attribute__((address_space(1))) void*)(gp),                    \
    (__attribute__((address_space(3))) void*)(lp), 16, 0, 0)

// counted vmcnt with compiler memory fence (prevents LDS reads hoisting above)
#define WAITVM(N) asm volatile("s_waitcnt vmcnt(" #N ")" ::: "memory")

__device__ __forceinline__ u16 f2bf(float f) {
  union { float f; unsigned u; } x; x.f = f;
  unsigned r = x.u + 0x7fffu + ((x.u >> 16) & 1u);
  return (u16)(r >> 16);
}

// ---------------- fused producer: transpose + modulate in one dispatch ----------------
// (unchanged — control group)
__global__ __launch_bounds__(256) void prep_fused(
    const float* __restrict__ fm, const float* __restrict__ w,
    const float* __restrict__ style, u16* __restrict__ xt,
    u16* __restrict__ wm, int b0)
{
  __shared__ __align__(16) char smraw[18448];     // union: 64*33 f32 | 4608+4 f32
  const int bid = blockIdx.x;
  const int g = bid / 3, rrole = bid - g * 3;
  const int tid = threadIdx.x;

  if (rrole < 2) {
    float* sm = (float*)smraw;                    // 64*33 floats
    const int ti = g * 2 + rrole;
    const int y = ti & 63, cg = (ti >> 6) & 15, bl = ti >> 10;
    const int x = tid & 63, cq = tid >> 6;
    const float* src = fm + (((size_t)(b0 + bl) * 512 + cg * 32) * 64 + y) * 64;
#pragma unroll
    for (int j = 0; j < 8; ++j) {
      int ci = j * 4 + cq;
      sm[x * 33 + ci] = src[(size_t)ci * 4096 + x];   // coalesced along x
    }

    u16* cgbase = xt + (size_t)(bl * 16 + cg) * XT_CGELEMS;
    const uint4 z = {0u, 0u, 0u, 0u};
    u16* rowb = cgbase + (size_t)(y + 1) * XT_ROWELEMS;
    if (tid < 4)              ((uint4*)rowb)[tid] = z;                  // col 0
    else if (tid < 8)         ((uint4*)(rowb + 65 * 32))[tid - 4] = z;  // col 65
    if (y == 0)  for (int i = tid; i < 264; i += 256) ((uint4*)cgbase)[i] = z;
    if (y == 63) for (int i = tid; i < 264; i += 256) ((uint4*)(cgbase + 65 * XT_ROWELEMS))[i] = z;

    __syncthreads();
    union { u16 s[8]; uint4 v; } u;
#pragma unroll
    for (int j = 0; j < 8; ++j) {
      int e = tid * 8 + j;                            // e = x*32 + c32
      u.s[j] = f2bf(sm[(e >> 5) * 33 + (e & 31)]);
    }
    const int col = 1 + (tid >> 2);
    const int slot = (tid & 3) ^ ((col >> 1) & 3);
    ((uint4*)rowb)[col * 4 + slot] = u.v;
  } else {
    float* sv = (float*)smraw;                    // 4608 floats
    float* red = (float*)(smraw + 18432);         // 4 floats
    const int o = g & 511, bl = g >> 9;
    const float gain = 0.014731391f;              // 1/sqrt(512*9)
    const float* wo = w + (size_t)o * 4608;       // flat idx = ci*9 + t
    const float* st = style + (size_t)(b0 + bl) * 512;
    float ss = 0.f;
#pragma unroll
    for (int j = 0; j < 18; ++j) {
      int idx = j * 256 + tid;
      float v = wo[idx] * gain * st[idx / 9];
      sv[idx] = v;
      ss += v * v;
    }
#pragma unroll
    for (int off = 32; off > 0; off >>= 1) ss += __shfl_down(ss, off, 64);
    if ((tid & 63) == 0) red[tid >> 6] = ss;
    __syncthreads();
    float sinv = rsqrtf(red[0] + red[1] + red[2] + red[3] + 1e-8f);
    const int axor = ((o >> 1) & 3) << 3;         // pre-swizzle for conv A-reads
    u16* base = wm + (size_t)bl * WM_ELEMS + (size_t)o * 32;
#pragma unroll
    for (int j = 0; j < 18; ++j) {
      int e = j * 256 + tid;                      // e = t*512 + c
      int t = e >> 9, c = e & 511;
      base[((size_t)(t * 16 + (c >> 5))) * 16384 + ((c & 31) ^ axor)] = f2bf(sv[c * 9 + t] * sinv);
    }
  }
}

// ---------------- kernel 3: implicit-GEMM conv, 2-fat-phase schedule ----------------
// 256x256 C tile, 512 threads = 8 waves (2M x 4N), per-wave 128x64.
// Per c32-step: ALL 12 frag ds_reads + stage issues at step top, then
// {barrier; lgkmcnt(4); 16 MFMA (mt0-3)} {barrier; lgkmcnt(0); 16 MFMA (mt4-7)}
// {vmcnt(N); barrier}. 3 barriers/step, one ~latency stall/step, 16 MFMA per
// phase per wave (the R4 post-mortem model: util ≈ MFMA/(MFMA+stall)).
// A tri-buffered depth-2 prefetch; B double-buffered, 4 loads spread t=3..6;
// counted vmcnt from exact per-wave FIFO (issue order per step: Ak0,Ak1,[B]).
__global__ __launch_bounds__(512, 2) void conv_mfma(
    const u16* __restrict__ Wmod, const u16* __restrict__ xt,
    float* __restrict__ out, int b0, int nb)
{
  const int id = blockIdx.x;
  const int bl = id % nb;                           // batch -> XCD (round-robin dispatch)
  const int rest = id / nb;                         // 0..31
  const int og = rest & 1, p_blk = rest >> 1;       // og: 256-row M half; p_blk: 256-px tile
  const int tid = threadIdx.x;
  const int lane = tid & 63, wave = tid >> 6;       // 8 waves
  const int wm_off = (wave & 1) * 128, wn_off = (wave >> 1) * 64;
  const int l15 = lane & 15, quad = lane >> 4;

  __shared__ __align__(16) u16 As[3][8192];         // 3 x 16 KB A k-slices (256 rows x 32)
  __shared__ __align__(16) u16 Bs[2][12672];        // 2 x [r6][col66][c32] = 2 x 25344 B

  const int y0 = p_blk * 4;                         // 4 pixel-rows + 2 halo = 6 xt rows
  const size_t xt_base = ((size_t)(bl * 16) * XT_CGELEMS) + (size_t)y0 * XT_ROWELEMS;
  const size_t w_base = (size_t)bl * WM_ELEMS + (size_t)og * (256 * 32);

  // B stage: 25344 B contiguous = 1584 16B-slots; wave w owns slots [w*198, +198):
  // 3 full GLDS + 1 partial (6 lanes). Every wave issues 4 -> equal vmcnt counts.
  auto stage_b = [&](int cg, int half, int k) {
    const char* g = (const char*)(xt + xt_base + (size_t)cg * XT_CGELEMS);
    char* l = (char*)Bs[half];
    const int off = wave * 3168 + k * 1024;         // 198*16 = 3168
    if (k < 3)            GLDS(g + off + lane * 16, l + off);
    else if (lane < 6)    GLDS(g + off + lane * 16, l + off);
  };
  // A stage: 16 KB contiguous; 1 GLDS per call (k = 0,1), 8 waves x 1024 B each.
  auto stage_a = [&](int t, int cg, int buf, int k) {
    const char* g = (const char*)(Wmod + w_base + (size_t)(t * 16 + cg) * 16384);
    const int off = k * 8192 + wave * 1024;
    GLDS(g + off + lane * 16, (char*)As[buf] + off);
  };

  // loop-invariant swizzled fragment addresses (verified rounds 1-4, conflicts = 0)
  int aoff[8];
#pragma unroll
  for (int mt = 0; mt < 8; ++mt) {
    int row = wm_off + mt * 16 + l15;
    aoff[mt] = row * 32 + ((quad ^ ((row >> 1) & 3)) << 3);
  }
  int pr[4], pc[4];
#pragma unroll
  for (int nt = 0; nt < 4; ++nt) {
    int p = wn_off + nt * 16 + l15;                 // 0..255
    pr[nt] = p >> 6; pc[nt] = p & 63;
  }

  floatx4 acc[8][4];
  const floatx4 zf = {0.f, 0.f, 0.f, 0.f};
#pragma unroll
  for (int mt = 0; mt < 8; ++mt)
#pragma unroll
    for (int nt = 0; nt < 4; ++nt) acc[mt][nt] = zf;

// one K-step: reads at top (12 ds_read: bfr0-3 then afr0-7), stages issued,
// then two fat phases of 16 MFMA, then counted vmcnt + closing barrier.
#define STEP(BCUR, CUR, STAGE0, STAGE1, STAGEB, VMSTMT)                        \
  {                                                                            \
    const u16* Acur = As[CUR];                                                 \
    s16x8 bfr[4], afr[8];                                                      \
    _Pragma("unroll")                                                          \
    for (int nt = 0; nt < 4; ++nt) {                                           \
      int r = pr[nt] + ky, c = pc[nt] + kx;                                    \
      bfr[nt] = *(const s16x8*)&BCUR[(r * 66 + c) * 32 +                       \
                                     ((quad ^ ((c >> 1) & 3)) << 3)];          \
    }                                                                          \
    _Pragma("unroll")                                                          \
    for (int mt = 0; mt < 8; ++mt)                                             \
      afr[mt] = *(const s16x8*)&Acur[aoff[mt]];                                \
    STAGE0; STAGE1; STAGEB;                                                    \
    __builtin_amdgcn_s_barrier();                                              \
    asm volatile("s_waitcnt lgkmcnt(4)");                                      \
    __builtin_amdgcn_sched_barrier(0);                                         \
    __builtin_amdgcn_s_setprio(1);                                             \
    _Pragma("unroll")                                                          \
    for (int mt = 0; mt < 4; ++mt)                                             \
      _Pragma("unroll")                                                        \
      for (int nt = 0; nt < 4; ++nt)                                           \
        acc[mt][nt] = __builtin_amdgcn_mfma_f32_16x16x32_bf16(                 \
            afr[mt], bfr[nt], acc[mt][nt], 0, 0, 0);                           \
    __builtin_amdgcn_s_setprio(0);                                             \
    __builtin_amdgcn_s_barrier();                                              \
    asm volatile("s_waitcnt lgkmcnt(0)");                                      \
    __builtin_amdgcn_sched_barrier(0);                                         \
    __builtin_amdgcn_s_setprio(1);                                             \
    _Pragma("unroll")                                                          \
    for (int mt = 4; mt < 8; ++mt)                                             \
      _Pragma("unroll")                                                        \
      for (int nt = 0; nt < 4; ++nt)                                           \
        acc[mt][nt] = __builtin_amdgcn_mfma_f32_16x16x32_bf16(                 \
            afr[mt], bfr[nt], acc[mt][nt], 0, 0, 0);                           \
    __builtin_amdgcn_s_setprio(0);                                             \
    VMSTMT;                                                                    \
    __builtin_amdgcn_s_barrier();                                              \
  }
#define SA0 stage_a(t2, cg2, nx2, 0)
#define SA1 stage_a(t2, cg2, nx2, 1)
#define NOSTG (void)0

  // prologue: B(0) [4 loads] + A(t0) [2] + A(t1) [2]; wait leaves A(t1) in flight
  stage_b(0, 0, 0); stage_b(0, 0, 1); stage_b(0, 0, 2); stage_b(0, 0, 3);
  stage_a(0, 0, 0, 0); stage_a(0, 0, 0, 1);
  stage_a(1, 0, 1, 0); stage_a(1, 0, 1, 1);
  WAITVM(2);
  __builtin_amdgcn_s_barrier();

#pragma unroll 1
  for (int cg = 0; cg < 15; ++cg) {
    const int cgp = cg & 1, cgn = cgp ^ 1;
    const u16* Bcur = Bs[cgp];
#pragma unroll
    for (int t = 0; t < 9; ++t) {
      const int cur = t % 3, nx2 = (t + 2) % 3;     // s%3 == t%3 (9 ≡ 0 mod 3)
      const int t2 = (t + 2 < 9) ? t + 2 : t - 7;   // step s+2 coords
      const int cg2 = (t + 2 < 9) ? cg : cg + 1;
      const int ky = t / 3, kx = t - ky * 3;
      // end-of-step vmcnt N = outstanding loads newer than A(s+1)k1 (exact FIFO;
      // per-step issue order Ak0, Ak1, [B]):
      if (t <= 2)       STEP(Bcur, cur, SA0, SA1, NOSTG, WAITVM(2))
      else if (t == 3)  STEP(Bcur, cur, SA0, SA1, stage_b(cg + 1, cgn, 0), WAITVM(3))
      else if (t <= 6)  STEP(Bcur, cur, SA0, SA1, stage_b(cg + 1, cgn, t - 3), WAITVM(4))
      else if (t == 7)  STEP(Bcur, cur, SA0, SA1, NOSTG, WAITVM(3))
      else              STEP(Bcur, cur, SA0, SA1, NOSTG, WAITVM(2))
    }
  }
  { // tail cg = 15: no B staging; A staging while s+2 exists (t <= 6)
    const u16* Bcur = Bs[15 & 1];
#pragma unroll
    for (int t = 0; t < 9; ++t) {
      const int cur = t % 3, nx2 = (t + 2) % 3;
      const int ky = t / 3, kx = t - ky * 3;
      if (t <= 6)       STEP(Bcur, cur, stage_a(t + 2, 15, nx2, 0),
                             stage_a(t + 2, 15, nx2, 1), NOSTG, WAITVM(2))
      else if (t == 7)  STEP(Bcur, cur, NOSTG, NOSTG, NOSTG, WAITVM(0))
      else              STEP(Bcur, cur, NOSTG, NOSTG, NOSTG, NOSTG)
    }
  }
#undef STEP
#undef SA0
#undef SA1
#undef NOSTG

  // epilogue: C/D layout col=lane&15, row=quad*4+reg (m89-verified)
  float* outp = out + ((size_t)(b0 + bl) * 512 + og * 256) * 4096 + p_blk * 256;
#pragma unroll
  for (int mt = 0; mt < 8; ++mt)
#pragma unroll
    for (int nt = 0; nt < 4; ++nt) {
      int n = wn_off + nt * 16 + l15;
#pragma unroll
      for (int r = 0; r < 4; ++r) {
        int m = wm_off + mt * 16 + quad * 4 + r;
        outp[(size_t)m * 4096 + n] = acc[mt][nt][r];
      }
    }
}

// ---------------- fallback: zero-workspace direct conv (R6, known-PASS) ----------------
__global__ __launch_bounds__(256) void conv_direct(
    const float* __restrict__ fm, const float* __restrict__ style,
    const float* __restrict__ w, float* __restrict__ out)
{
  const int o = blockIdx.x, b = blockIdx.y, tid = threadIdx.x;
  __shared__ float swm[4608];
  __shared__ float red[4];
  const float gain = 0.014731391f;
  const float* wo = w + (size_t)o * 4608;
  const float* st = style + (size_t)b * 512;
  float ss = 0.f;
#pragma unroll
  for (int j = 0; j < 18; ++j) {
    int idx = j * 256 + tid;
    float v = wo[idx] * gain * st[idx / 9];
    swm[idx] = v;
    ss += v * v;
  }
#pragma unroll
  for (int off = 32; off > 0; off >>= 1) ss += __shfl_down(ss, off, 64);
  if ((tid & 63) == 0) red[tid >> 6] = ss;
  __syncthreads();
  const float sinv = rsqrtf(red[0] + red[1] + red[2] + red[3] + 1e-8f);

  const int y = tid >> 2, x0 = (tid & 3) * 16;
  float acc[16];
#pragma unroll
  for (int i = 0; i < 16; ++i) acc[i] = 0.f;
  const float* fb = fm + (size_t)b * 512 * 4096;
  for (int ci = 0; ci < 512; ++ci) {
    const float* fc = fb + (size_t)ci * 4096;
    const float* wr = swm + ci * 9;
#pragma unroll
    for (int ky = 0; ky < 3; ++ky) {
      int yy = y + ky - 1;
      if (yy < 0 || yy > 63) continue;
      const float* frow = fc + yy * 64;
#pragma unroll
      for (int kx = 0; kx < 3; ++kx) {
        float wv = wr[ky * 3 + kx];
#pragma unroll
        for (int i = 0; i < 16; ++i) {
          int xx = x0 + i + kx - 1;
          float xv = (xx >= 0 && xx < 64) ? frow[xx] : 0.f;
          acc[i] += wv * xv;
        }
      }
    }
  }
  float* op = out + ((size_t)b * 512 + o) * 4096 + y * 64 + x0;
#pragma unroll
  for (int i = 0; i < 16; ++i) op[i] = acc[i] * sinv;
}

extern "C" void kernel_launch(void* const* d_in, const int* in_sizes, int n_in,
                              void* d_out, int out_size, void* d_ws, size_t ws_size,
                              hipStream_t stream) {
  const float* fm = (const float*)d_in[0];     // (8,512,64,64) fp32
  const float* style = (const float*)d_in[1];  // (8,512) fp32
  const float* w = (const float*)d_in[2];      // (512,512,3,3) fp32
  float* out = (float*)d_out;                  // (8,512,64,64) fp32

  if (ws_size < XT_PB + WM_PB) {               // workspace too small: direct path
    conv_direct<<<dim3(512, 8), 256, 0, stream>>>(fm, style, w, out);
    return;
  }
  int nb = 8;
  while (nb > 1 && (size_t)nb * (XT_PB + WM_PB) > ws_size) nb >>= 1;

  u16* xt = (u16*)d_ws;
  u16* wmod = (u16*)((char*)d_ws + (size_t)nb * XT_PB);

  for (int b0 = 0; b0 < 8; b0 += nb) {
    prep_fused<<<dim3(1536 * nb), 256, 0, stream>>>(fm, w, style, xt, wmod, b0);
    conv_mfma<<<dim3(32 * nb), 512, 0, stream>>>(wmod, xt, out, b0, nb);
  }
}

// Round 6
// 267.365 us; speedup vs baseline: 1.0998x; 1.0998x over previous
//
#include <hip/hip_runtime.h>

typedef unsigned short u16;
typedef __attribute__((ext_vector_type(8))) short s16x8;   // 8 x bf16 frag (verified form)
typedef __attribute__((ext_vector_type(4))) float floatx4;

// xt (per batch): [cg=16][row=66][col=66][c32=32] bf16, spatial-padded NCHW32c
// SWIZZLED: within each 64B (row,col) channel-group, c32 index ^= ((col>>1)&3)<<3
#define XT_ROWELEMS 2112                 // 66*32
#define XT_CGELEMS  139392               // 66*66*32
#define XT_PB       4460544ull           // 16*66*66*32*2 bytes per batch
// wmod (per batch): [t=9][cg=16][o512=512][c32=32] bf16  (o512 contiguous for M=256 tiles)
// SWIZZLED: within each 64B o-row, c32 index ^= ((o>>1)&3)<<3
#define WM_ELEMS    2359296ull           // 9*16*512*32 elems per batch
#define WM_PB       4718592ull           // bytes per batch

// async global->LDS DMA, 16B per lane; lds dest = wave-uniform base + lane*16
#define GLDS(gp, lp) __builtin_amdgcn_global_load_lds(                      \
    (const __attribute__((address_space(1))) void*)(gp),                    \
    (__attribute__((address_space(3))) void*)(lp), 16, 0, 0)

__device__ __forceinline__ u16 f2bf(float f) {
  union { float f; unsigned u; } x; x.f = f;
  unsigned r = x.u + 0x7fffu + ((x.u >> 16) & 1u);
  return (u16)(r >> 16);
}

// ---------------- fused producer: transpose + modulate, vectorized memory path ----------------
// grid (1536*nb), 256 threads. Roles interleaved (bid%3): 2 transpose : 1 modulate.
// v2: float4 global loads (16B/lane, G13), bf16-convert BEFORE LDS (halved LDS bytes,
// ds_read_b128 on output path), ds_write_b128 in modulate, paired u32 wmod stores.
// Byte layouts of xt/wmod identical to the verified split kernels.
__global__ __launch_bounds__(256) void prep_fused(
    const float* __restrict__ fm, const float* __restrict__ w,
    const float* __restrict__ style, u16* __restrict__ xt,
    u16* __restrict__ wm, int b0)
{
  __shared__ __align__(16) char smraw[18448];     // union: 64x40 u16 | 4608+4 f32
  const int bid = blockIdx.x;
  const int g = bid / 3, rrole = bid - g * 3;
  const int tid = threadIdx.x;

  if (rrole < 2) {
    // ---------- transpose body: fm (NCHW f32) -> xt (padded NCHW32c bf16, pre-swizzled) ----------
    u16* sm16 = (u16*)smraw;                      // [x=64][ci=32] pad 40 (16B-aligned rows)
    const int ti = g * 2 + rrole;
    const int y = ti & 63, cg = (ti >> 6) & 15, bl = ti >> 10;
    const float* src = fm + (((size_t)(b0 + bl) * 512 + cg * 32) * 64 + y) * 64;
    const int x4 = (tid & 15) * 4;
#pragma unroll
    for (int it = 0; it < 2; ++it) {
      int ci = (tid >> 4) + it * 16;
      float4 v = *(const float4*)&src[(size_t)ci * 4096 + x4];   // 16B/lane coalesced
      sm16[(x4 + 0) * 40 + ci] = f2bf(v.x);
      sm16[(x4 + 1) * 40 + ci] = f2bf(v.y);
      sm16[(x4 + 2) * 40 + ci] = f2bf(v.z);
      sm16[(x4 + 3) * 40 + ci] = f2bf(v.w);
    }

    u16* cgbase = xt + (size_t)(bl * 16 + cg) * XT_CGELEMS;
    const uint4 z = {0u, 0u, 0u, 0u};
    u16* rowb = cgbase + (size_t)(y + 1) * XT_ROWELEMS;
    if (tid < 4)              ((uint4*)rowb)[tid] = z;                  // col 0
    else if (tid < 8)         ((uint4*)(rowb + 65 * 32))[tid - 4] = z;  // col 65
    if (y == 0)  for (int i = tid; i < 264; i += 256) ((uint4*)cgbase)[i] = z;
    if (y == 63) for (int i = tid; i < 264; i += 256) ((uint4*)(cgbase + 65 * XT_ROWELEMS))[i] = z;

    __syncthreads();
    // interior cols 1..64: thread writes one 16B slot = channels (tid&3)*8..+7
    // of col 1+(tid>>2). Pre-swizzle: slot ^= (col>>1)&3. One ds_read_b128.
    const int x = tid >> 2;
    uint4 u = *(const uint4*)&sm16[x * 40 + (tid & 3) * 8];
    const int col = 1 + x;
    const int slot = (tid & 3) ^ ((col >> 1) & 3);
    ((uint4*)rowb)[col * 4 + slot] = u;
  } else {
    // ---------- modulate body (o512 layout, pre-swizzled), vectorized ----------
    float* sv = (float*)smraw;                    // 4608 floats
    float* red = (float*)(smraw + 18432);         // 4 floats
    const int o = g & 511, bl = g >> 9;
    const float gain = 0.014731391f;              // 1/sqrt(512*9)
    const float* wo = w + (size_t)o * 4608;       // flat idx = ci*9 + t
    const float* st = style + (size_t)(b0 + bl) * 512;
    float ss = 0.f;
#pragma unroll
    for (int j = 0; j < 5; ++j) {                 // 1152 float4 slots over 256 thr
      int s4 = j * 256 + tid;
      if (s4 < 1152) {
        float4 v = *(const float4*)&wo[s4 * 4];   // 16B/lane coalesced
        int i0 = s4 * 4;
        int c0 = i0 / 9, rem = i0 - c0 * 9;       // ci of v.x
        float sa = st[c0];
        float sb = st[c0 < 511 ? c0 + 1 : 511];   // clamp: unused when c0==511
        float w0 = v.x * gain * sa;               // rem+0 < 9 always
        float w1 = v.y * gain * (rem + 1 >= 9 ? sb : sa);
        float w2 = v.z * gain * (rem + 2 >= 9 ? sb : sa);
        float w3 = v.w * gain * (rem + 3 >= 9 ? sb : sa);
        floatx4 wv = {w0, w1, w2, w3};
        ((floatx4*)sv)[s4] = wv;                  // ds_write_b128
        ss += w0 * w0 + w1 * w1 + w2 * w2 + w3 * w3;
      }
    }
#pragma unroll
    for (int off = 32; off > 0; off >>= 1) ss += __shfl_down(ss, off, 64);
    if ((tid & 63) == 0) red[tid >> 6] = ss;
    __syncthreads();
    float sinv = rsqrtf(red[0] + red[1] + red[2] + red[3] + 1e-8f);
    const int axor = ((o >> 1) & 3) << 3;         // pre-swizzle for conv A-reads
    u16* base = wm + (size_t)bl * WM_ELEMS + (size_t)o * 32;
    const int c0 = tid * 2;                       // even -> XOR keeps pair adjacent
    const int pos = (c0 & 31) ^ axor;             // even (axor has no bit0)
#pragma unroll
    for (int t = 0; t < 9; ++t) {                 // 9 paired u32 stores
      unsigned lo = f2bf(sv[c0 * 9 + t] * sinv);
      unsigned hi = f2bf(sv[(c0 + 1) * 9 + t] * sinv);
      *(unsigned*)(base + ((size_t)(t * 16 + (c0 >> 5))) * 16384 + pos) = lo | (hi << 16);
    }
  }
}

// ---------------- kernel 3: implicit-GEMM conv via bf16 MFMA (R2-exact, verified 159-166 us) ----------------
// grid 64*nb linear, 256 threads. C tile 256x128 per block, K=4608.
// Wave tile 128x64 (8x4 frags): 12 ds_read_b128 per 32 MFMA (ratio 2.67).
// 2 blocks/CU -> cross-block overlap hides the per-step barrier drain (m114).
// Swizzled LDS reads (conflicts = 0). DO NOT restructure: both phase-schedule
// ports (R4 4-thin-phase, R5 2-fat-phase) regressed (166 -> 183 -> 191 us).
__global__ __launch_bounds__(256, 2) void conv_mfma(
    const u16* __restrict__ Wmod, const u16* __restrict__ xt,
    float* __restrict__ out, int b0, int nb)
{
  const int id = blockIdx.x;
  const int bl = id % nb;                           // same batch -> same XCD (round robin)
  const int rest = id / nb;
  const int og = rest & 1, p_blk = rest >> 1;       // og: 256-row M chunk
  const int tid = threadIdx.x;
  const int lane = tid & 63, wave = tid >> 6;
  const int wm_off = (wave & 1) * 128, wn_off = (wave >> 1) * 64;
  const int l15 = lane & 15, quad = lane >> 4;

  __shared__ __align__(16) u16 As[2][8192];         // 2 x 16 KB A k-slices (256 rows x 32)
  __shared__ __align__(16) u16 Bs[8448];            // [r4][col66][c32] = 16896 B

  const int y0 = p_blk * 2;
  const size_t xt_base = ((size_t)(bl * 16) * XT_CGELEMS) + (size_t)y0 * XT_ROWELEMS;
  const size_t w_base = (size_t)bl * WM_ELEMS + (size_t)og * (256 * 32);

  auto stage_b = [&](int cg) {                      // 16896 B contiguous, async
    const char* g = (const char*)(xt + xt_base + (size_t)cg * XT_CGELEMS);
    for (int r = wave; r < 16; r += 4)
      GLDS(g + r * 1024 + lane * 16, (char*)Bs + r * 1024);
    if (wave == 0 && lane < 32)                     // 512 B tail
      GLDS(g + 16384 + lane * 16, (char*)Bs + 16384);
  };
  auto stage_a = [&](int t, int cg, int buf) {      // 16 KB contiguous, async (4 GLDS/wave)
    const char* g = (const char*)(Wmod + w_base + (size_t)(t * 16 + cg) * 16384);
    for (int r = wave; r < 16; r += 4)
      GLDS(g + r * 1024 + lane * 16, (char*)As[buf] + r * 1024);
  };

  // loop-invariant swizzled fragment addresses
  int aoff[8];
#pragma unroll
  for (int mt = 0; mt < 8; ++mt) {
    int row = wm_off + mt * 16 + l15;               // local o-row; global o = og*256+row
    aoff[mt] = row * 32 + ((quad ^ ((row >> 1) & 3)) << 3);  // same ((o>>1)&3) swizzle
  }
  int pr[4], pc[4];
#pragma unroll
  for (int nt = 0; nt < 4; ++nt) {
    int p = wn_off + nt * 16 + l15;
    pr[nt] = p >> 6; pc[nt] = p & 63;
  }

  floatx4 acc[8][4];
  const floatx4 zf = {0.f, 0.f, 0.f, 0.f};
#pragma unroll
  for (int mt = 0; mt < 8; ++mt)
#pragma unroll
    for (int nt = 0; nt < 4; ++nt) acc[mt][nt] = zf;

  stage_b(0);
  stage_a(0, 0, 0);
  __syncthreads();                                  // vmcnt drain -> data visible

#pragma unroll 1
  for (int cg = 0; cg < 16; ++cg) {
#pragma unroll 1
    for (int t = 0; t < 9; ++t) {
      const int cur = (cg * 9 + t) & 1, nxt = cur ^ 1;
      const bool last = (cg == 15 && t == 8);
      const bool cgb = (t == 8 && cg < 15);         // cg boundary
      if (!last) stage_a(t < 8 ? t + 1 : 0, t < 8 ? cg : cg + 1, nxt);  // async prefetch

      const int ky = t / 3, kx = t - ky * 3;
      s16x8 afr[8], bfr[4];
      const u16* Ab = As[cur];
#pragma unroll
      for (int nt = 0; nt < 4; ++nt) {              // B[n=lane&15][k=quad*8+j], swizzled
        int r = pr[nt] + ky, c = pc[nt] + kx;
        bfr[nt] = *(const s16x8*)&Bs[(r * 66 + c) * 32 + ((quad ^ ((c >> 1) & 3)) << 3)];
      }
#pragma unroll
      for (int mt = 0; mt < 8; ++mt)                // A[m=lane&15][k=quad*8+j], swizzled
        afr[mt] = *(const s16x8*)&Ab[aoff[mt]];
#pragma unroll
      for (int mt = 0; mt < 8; ++mt)
#pragma unroll
        for (int nt = 0; nt < 4; ++nt)
          acc[mt][nt] = __builtin_amdgcn_mfma_f32_16x16x32_bf16(
              afr[mt], bfr[nt], acc[mt][nt], 0, 0, 0);

      if (cgb) {
        __syncthreads();                            // all waves done reading Bs
        stage_b(cg + 1);                            // async restage
      }
      __syncthreads();                              // drains DMA; LDS visible
    }
  }

  // epilogue: C/D layout col=lane&15, row=quad*4+reg (m89-verified)
  float* outp = out + ((size_t)(b0 + bl) * 512 + og * 256) * 4096 + p_blk * 128;
#pragma unroll
  for (int mt = 0; mt < 8; ++mt)
#pragma unroll
    for (int nt = 0; nt < 4; ++nt) {
      int n = wn_off + nt * 16 + l15;
#pragma unroll
      for (int r = 0; r < 4; ++r) {
        int m = wm_off + mt * 16 + quad * 4 + r;
        outp[(size_t)m * 4096 + n] = acc[mt][nt][r];
      }
    }
}

// ---------------- fallback: zero-workspace direct conv (R6, known-PASS) ----------------
__global__ __launch_bounds__(256) void conv_direct(
    const float* __restrict__ fm, const float* __restrict__ style,
    const float* __restrict__ w, float* __restrict__ out)
{
  const int o = blockIdx.x, b = blockIdx.y, tid = threadIdx.x;
  __shared__ float swm[4608];
  __shared__ float red[4];
  const float gain = 0.014731391f;
  const float* wo = w + (size_t)o * 4608;
  const float* st = style + (size_t)b * 512;
  float ss = 0.f;
#pragma unroll
  for (int j = 0; j < 18; ++j) {
    int idx = j * 256 + tid;
    float v = wo[idx] * gain * st[idx / 9];
    swm[idx] = v;
    ss += v * v;
  }
#pragma unroll
  for (int off = 32; off > 0; off >>= 1) ss += __shfl_down(ss, off, 64);
  if ((tid & 63) == 0) red[tid >> 6] = ss;
  __syncthreads();
  const float sinv = rsqrtf(red[0] + red[1] + red[2] + red[3] + 1e-8f);

  const int y = tid >> 2, x0 = (tid & 3) * 16;
  float acc[16];
#pragma unroll
  for (int i = 0; i < 16; ++i) acc[i] = 0.f;
  const float* fb = fm + (size_t)b * 512 * 4096;
  for (int ci = 0; ci < 512; ++ci) {
    const float* fc = fb + (size_t)ci * 4096;
    const float* wr = swm + ci * 9;
#pragma unroll
    for (int ky = 0; ky < 3; ++ky) {
      int yy = y + ky - 1;
      if (yy < 0 || yy > 63) continue;
      const float* frow = fc + yy * 64;
#pragma unroll
      for (int kx = 0; kx < 3; ++kx) {
        float wv = wr[ky * 3 + kx];
#pragma unroll
        for (int i = 0; i < 16; ++i) {
          int xx = x0 + i + kx - 1;
          float xv = (xx >= 0 && xx < 64) ? frow[xx] : 0.f;
          acc[i] += wv * xv;
        }
      }
    }
  }
  float* op = out + ((size_t)b * 512 + o) * 4096 + y * 64 + x0;
#pragma unroll
  for (int i = 0; i < 16; ++i) op[i] = acc[i] * sinv;
}

extern "C" void kernel_launch(void* const* d_in, const int* in_sizes, int n_in,
                              void* d_out, int out_size, void* d_ws, size_t ws_size,
                              hipStream_t stream) {
  const float* fm = (const float*)d_in[0];     // (8,512,64,64) fp32
  const float* style = (const float*)d_in[1];  // (8,512) fp32
  const float* w = (const float*)d_in[2];      // (512,512,3,3) fp32
  float* out = (float*)d_out;                  // (8,512,64,64) fp32

  if (ws_size < XT_PB + WM_PB) {               // workspace too small: direct path
    conv_direct<<<dim3(512, 8), 256, 0, stream>>>(fm, style, w, out);
    return;
  }
  int nb = 8;
  while (nb > 1 && (size_t)nb * (XT_PB + WM_PB) > ws_size) nb >>= 1;

  u16* xt = (u16*)d_ws;
  u16* wmod = (u16*)((char*)d_ws + (size_t)nb * XT_PB);

  for (int b0 = 0; b0 < 8; b0 += nb) {
    prep_fused<<<dim3(1536 * nb), 256, 0, stream>>>(fm, w, style, xt, wmod, b0);
    conv_mfma<<<dim3(64 * nb), 256, 0, stream>>>(wmod, xt, out, b0, nb);
  }
}